// Round 12
// baseline (273.436 us; speedup 1.0000x reference)
//
#include <hip/hip_runtime.h>

// Correlation (FlowNet-style), kernel=1, stride=1, md=pad=4.
// B=8, C=128, H=W=192 -> out [8, 81, 192, 192] fp32.
//
// Round-12: two-kernel MFMA design, no LDS in the main loop.
//  K1 (prepass): cast+transpose x2 -> x2t[b][y][x][c] f16 in d_ws (75.5 MB).
//     Streaming, LDS-tile transpose with XOR swizzle (conflict-free both
//     sides), fully coalesced global read & write.
//  K2 (main): per block (b, 8y, 16x), 8 waves = y rows. Banded GEMM:
//     out[dx, p] = sum_c x1[p, c] * x2t[rho, p+dx, c].
//     - A-frags: x1 scalar f32 loads + cvt_pkrtz (R11-validated), all 4
//       K-chunks held in 16 VGPR.
//     - B-frags: DIRECT global f16x8 loads from x2t (c-contiguous) --
//       no LDS staging, no barriers, no bank conflicts. 9x dy reuse via L1.
//     - acc streams over dy: acc[2 jt] only (8 VGPR); after each dy the
//       band-valid lanes store straight to out (predicated 4-B stores;
//       each (plane,y) row gets its full 64-B line -> L2 write-combines).
//  Fallback: if ws_size < 75.5 MB, run the R11 kernel (verbatim) instead.

typedef __fp16 f16x8 __attribute__((ext_vector_type(8)));
typedef __fp16 p2 __attribute__((ext_vector_type(2)));
typedef float f32x4 __attribute__((ext_vector_type(4)));

union PK { p2 p; unsigned u; };
union FragA { f16x8 v; p2 p[4]; };
union B16 { f16x8 v; uint4 q; };

static __device__ __forceinline__ unsigned pku(float a, float b) {
  PK z; z.p = __builtin_amdgcn_cvt_pkrtz(a, b); return z.u;
}

// ---------------------------------------------------------------- prepass
__global__ __launch_bounds__(256)
void transpose_k(const float* __restrict__ x2g, __fp16* __restrict__ x2t) {
  constexpr int Hh = 192, Ww = 192, Cc = 128;
  __shared__ float lds[128 * 36];  // 18.4 KB, row stride 36 (16B-aligned)

  const int bid = blockIdx.x;
  const int xt = bid % 6;
  const int y  = (bid / 6) % Hh;
  const int b  = bid / (6 * Hh);
  const int x0 = xt * 32;
  const int t  = (int)threadIdx.x;

  // load 128c x 32x f32, swizzled LDS write (conflict-free)
#pragma unroll
  for (int i = 0; i < 4; ++i) {
    const int idx = i * 256 + t;
    const int c = idx >> 3, xq = idx & 7;
    const float4 v =
        *(const float4*)(x2g + ((size_t)(b * Cc + c) * Hh + y) * Ww + x0 + 4 * xq);
    *(float4*)&lds[c * 36 + 4 * (xq ^ ((c >> 3) & 7))] = v;
  }
  __syncthreads();

  // pack 8 c's per (x, oct) and store c-contiguous (coalesced 16B/lane)
  const int oct = t & 15, xl = t >> 4;
#pragma unroll
  for (int pass = 0; pass < 2; ++pass) {
    const int x = xl + 16 * pass;
    float f[8];
#pragma unroll
    for (int k = 0; k < 8; ++k)
      f[k] = lds[(oct * 8 + k) * 36 + 4 * ((x >> 2) ^ (oct & 7)) + (x & 3)];
    uint4 u;
    u.x = pku(f[0], f[1]); u.y = pku(f[2], f[3]);
    u.z = pku(f[4], f[5]); u.w = pku(f[6], f[7]);
    *(uint4*)(x2t + ((size_t)(b * Hh + y) * Ww + x0 + x) * Cc + oct * 8) = u;
  }
}

// ---------------------------------------------------------------- main
__global__ __launch_bounds__(512, 4)
void corr_main(const float* __restrict__ x1g, const __fp16* __restrict__ x2t,
               float* __restrict__ outg) {
  constexpr int Cc = 128, Hh = 192, Ww = 192;
  constexpr int HW = Hh * Ww;

  // XCD-chunked swizzle: 2304 = 8 XCDs x 288; yt fastest.
  const int bid = blockIdx.x;
  const int wid = (bid & 7) * 288 + (bid >> 3);
  const int yt = wid % 24;
  const int t2 = wid / 24;
  const int xbk = t2 % 12;
  const int b = t2 / 12;
  const int y0 = yt * 8, x0 = xbk * 16;

  const int tid = (int)threadIdx.x;
  const int wy = tid >> 6;
  const int lane = tid & 63;
  const int lr = lane & 15;
  const int lq = lane >> 4;

  // ---- A fragments: x1[c][y0+wy][x0+lr], c = kc*32 + lq*8 + e ----
  FragA af[4];
  {
    const float* pA = x1g + (((size_t)b * Cc) * Hh + (y0 + wy)) * Ww + x0 + lr;
#pragma unroll
    for (int kc = 0; kc < 4; ++kc)
#pragma unroll
      for (int r = 0; r < 4; ++r) {
        const int c0 = kc * 32 + lq * 8 + 2 * r;
        af[kc].p[r] = __builtin_amdgcn_cvt_pkrtz(pA[(size_t)c0 * HW],
                                                 pA[(size_t)(c0 + 1) * HW]);
      }
  }

  // ---- B lane offsets (halfs) for jt 0/1, with col masks ----
  const int j0 = x0 - 4 + lr;   // jt0 global col; <0 possible, <=187 always
  const int j1 = x0 + 12 + lr;  // jt1 global col; >=12 always, >191 possible
  const bool m0 = (j0 >= 0);
  const bool m1 = (j1 <= Ww - 1);
  const int o0 = (m0 ? j0 : 0) * Cc + lq * 8;
  const int o1 = (m1 ? j1 : 0) * Cc + lq * 8;

  B16 zz; zz.q.x = zz.q.y = zz.q.z = zz.q.w = 0u;
  const f16x8 fz = zz.v;

  const float invc = 1.0f / 128.0f;
  const int ybase = y0 + wy;
  const size_t outb = ((size_t)b * 81 * Hh + ybase) * Ww + x0;

  for (int dy = 0; dy < 9; ++dy) {
    f32x4 a0 = {0.f, 0.f, 0.f, 0.f};
    f32x4 a1 = {0.f, 0.f, 0.f, 0.f};
    const int rg = y0 + wy + dy - 4;  // x2 row (wave-uniform)
    if (rg >= 0 && rg < Hh) {
      const __fp16* rp = x2t + (size_t)(b * Hh + rg) * Ww * Cc;
#pragma unroll
      for (int kc = 0; kc < 4; ++kc) {
        f16x8 b0 = fz, b1 = fz;
        if (m0) b0 = *(const f16x8*)(rp + o0 + kc * 32);
        if (m1) b1 = *(const f16x8*)(rp + o1 + kc * 32);
        a0 = __builtin_amdgcn_mfma_f32_16x16x32_f16(af[kc].v, b0, a0, 0, 0, 0);
        a1 = __builtin_amdgcn_mfma_f32_16x16x32_f16(af[kc].v, b1, a1, 0, 0, 0);
      }
    }
    // predicated band stores: D[row = 4lq+r][col = jt*16+lr], dx = col - row
    const size_t db = outb + (size_t)dy * 9 * HW;
#pragma unroll
    for (int r = 0; r < 4; ++r) {
      const int p = 4 * lq + r;
      const int dx0 = lr - p;
      const int dx1 = 16 + lr - p;
      if (dx0 >= 0 && dx0 <= 8) outg[db + (size_t)dx0 * HW + p] = a0[r] * invc;
      if (dx1 <= 8)             outg[db + (size_t)dx1 * HW + p] = a1[r] * invc;
    }
  }
}

// ---------------------------------------------------------------- fallback
// R11 kernel verbatim (used only if ws_size < 75.5 MB).
__global__ __launch_bounds__(512, 4)
void corr_fb(const float* __restrict__ x1g, const float* __restrict__ x2g,
             float* __restrict__ outg) {
  constexpr int Cc = 128, Hh = 192, Ww = 192;
  constexpr int HW = Hh * Ww;

  __shared__ __align__(16) char smem[65536];
  unsigned* sm32 = (unsigned*)smem;

  const int bid = blockIdx.x;
  const int wid = (bid & 7) * 288 + (bid >> 3);
  const int yt = wid % 24;
  const int t2 = wid / 24;
  const int xbk = t2 % 12;
  const int b = t2 / 12;
  const int y0 = yt * 8, x0 = xbk * 16;

  const int tid = (int)threadIdx.x;
  const int wy = tid >> 6;
  const int lane = tid & 63;
  const int lr = lane & 15;
  const int lq = lane >> 4;

  FragA af[4];
  {
    const float* pA = x1g + (((size_t)b * Cc) * Hh + (y0 + wy)) * Ww + x0 + lr;
#pragma unroll
    for (int kc = 0; kc < 4; ++kc)
#pragma unroll
      for (int r = 0; r < 4; ++r) {
        const int c0 = kc * 32 + lq * 8 + 2 * r;
        af[kc].p[r] = __builtin_amdgcn_cvt_pkrtz(pA[(size_t)c0 * HW],
                                                 pA[(size_t)(c0 + 1) * HW]);
      }
  }

  const float* bsrc[3];
  int loff[3];
  bool bok[3];
#pragma unroll
  for (int k = 0; k < 3; ++k) {
    const int s = tid + k * 512;
    const int jf = s % 6;
    const int t = s / 6;
    const int cpair = t & 15;
    const int rho = t >> 4;
    const int grow = y0 - 4 + rho;
    const int gcol = x0 - 4 + 4 * jf;
    const bool ok = (grow >= 0) && (grow < Hh) && (gcol >= 0) && (gcol <= Ww - 4);
    bok[k] = ok;
    bsrc[k] = x2g + ((size_t)(b * Cc + 2 * cpair) * Hh + (ok ? grow : 0)) * Ww +
              (ok ? gcol : 0);
    loff[k] = rho * 512 + jf * 64 + cpair;
  }

  unsigned pk[3][4];
  auto bload = [&](int kc) {
#pragma unroll
    for (int k = 0; k < 3; ++k) {
      float4 v0 = make_float4(0.f, 0.f, 0.f, 0.f), v1 = v0;
      if (bok[k]) {
        const float* p = bsrc[k] + (size_t)(kc * 32) * HW;
        v0 = *(const float4*)p;
        v1 = *(const float4*)(p + HW);
      }
      pk[k][0] = pku(v0.x, v1.x);
      pk[k][1] = pku(v0.y, v1.y);
      pk[k][2] = pku(v0.z, v1.z);
      pk[k][3] = pku(v0.w, v1.w);
    }
  };
  auto bwrite = [&](int buf) {
    unsigned* d = sm32 + buf * 8192;
#pragma unroll
    for (int k = 0; k < 3; ++k)
#pragma unroll
      for (int kk = 0; kk < 4; ++kk)
        d[loff[k] + kk * 16] = pk[k][kk];
  };

  f32x4 acc[9][2];
#pragma unroll
  for (int dy = 0; dy < 9; ++dy)
#pragma unroll
    for (int jt = 0; jt < 2; ++jt)
      acc[dy][jt] = (f32x4){0.f, 0.f, 0.f, 0.f};

  bload(0);
  bwrite(0);
  bload(1);

  const int rb = lr * 64 + lq * 16;

#pragma unroll
  for (int kc = 0; kc < 4; ++kc) {
    __syncthreads();
    if (kc + 1 < 4) bwrite((kc + 1) & 1);
    if (kc + 2 < 4) bload(kc + 2);
    const char* base = smem + (kc & 1) * 32768;
#pragma unroll
    for (int dy = 0; dy < 9; ++dy) {
      const char* rp = base + (wy + dy) * 2048 + rb;
#pragma unroll
      for (int jt = 0; jt < 2; ++jt) {
        const f16x8 bf = *(const f16x8*)(rp + jt * 1024);
        acc[dy][jt] = __builtin_amdgcn_mfma_f32_16x16x32_f16(
            af[kc].v, bf, acc[dy][jt], 0, 0, 0);
      }
    }
  }

  __syncthreads();
  float* ot = (float*)smem;
  const float invc = 1.0f / 128.0f;
#pragma unroll
  for (int dy = 0; dy < 9; ++dy)
#pragma unroll
    for (int jt = 0; jt < 2; ++jt)
#pragma unroll
      for (int r = 0; r < 4; ++r) {
        const int p = 4 * lq + r;
        const int dx = jt * 16 + lr - p;
        if (dx >= 0 && dx < 9)
          ot[((dy * 9 + dx) * 8 + wy) * 16 + p] = acc[dy][jt][r] * invc;
      }
  __syncthreads();

  for (int s = tid; s < 2592; s += 512) {
    const int d = s >> 5;
    const int yy = (s >> 2) & 7;
    const int xf = s & 3;
    const float4 v = *(const float4*)&ot[d * 128 + yy * 16 + xf * 4];
    *(float4*)&outg[(((size_t)b * 81 + d) * Hh + (y0 + yy)) * Ww + x0 + xf * 4] = v;
  }
}

extern "C" void kernel_launch(void* const* d_in, const int* in_sizes, int n_in,
                              void* d_out, int out_size, void* d_ws, size_t ws_size,
                              hipStream_t stream) {
  const float* x1 = (const float*)d_in[0];
  const float* x2 = (const float*)d_in[1];
  float* out = (float*)d_out;
  const size_t need = (size_t)8 * 192 * 192 * 128 * 2;  // x2t f16: 75.5 MB
  if (ws_size >= need) {
    __fp16* x2t = (__fp16*)d_ws;
    // prepass: 8b x 192y x 6 x-tiles = 9216 blocks
    transpose_k<<<dim3(9216), dim3(256), 0, stream>>>(x2, x2t);
    // main: 8b x 24yt x 12xt = 2304 blocks (divisible by 8 XCDs)
    corr_main<<<dim3(2304), dim3(512), 0, stream>>>(x1, x2t, out);
  } else {
    corr_fb<<<dim3(2304), dim3(512), 0, stream>>>(x1, x2, out);
  }
}

// Round 13
// 202.891 us; speedup vs baseline: 1.3477x; 1.3477x over previous
//
#include <hip/hip_runtime.h>

// Correlation (FlowNet-style), kernel=1, stride=1, md=pad=4.
// B=8, C=128, H=W=192 -> out [8, 81, 192, 192] fp32.
//
// Round-13: MFMA band-GEMM, occupancy-first microblocks.
//  - Work unit: (b, 4y-strip, 16x, dy-triple). Block = 256 thr = 4 waves
//    (wave = y row). Grid = 8b x 12xt x 48yt x 3dyg = 13824 blocks (54/CU).
//  - Per wave: acc[3 dy][2 jt] f32x4 = 24 regs; af[4 kc] = 16 regs ->
//    ~95 peak regs, launch_bounds(256,5) caps at 102 -> 20 waves/CU
//    (vs R11's 13). Goal: enough in-flight loads to feed HBM.
//  - x2 LDS: [6 rho][24 j][16 cpair] uints per chunk (32 c), double-buffered
//    (20.5 KB); cpair-quad XOR swizzle (cq ^= jf&3) cuts write conflicts,
//    read provably returns channels 8lq..8lq+7 (cq==lq after XOR cancel).
//  - B-frag reads: dense 1 KB/wave ds_read_b128 (same as R11, bank-optimal).
//  - jt1 cols j>=24 read staged-garbage -> only feed dx>8 lanes (discarded);
//    garbage is finite-or-NaN but never stored.
//  - XCD swizzle: XCD k == batch k exactly; dy-triples + adjacent yt
//    co-resident -> x1 3x re-read and x2 halos served by L2.
//  - Epilogue: band scatter -> 6.9 KB LDS out-tile -> coalesced float4.

#define NT 256

typedef __fp16 f16x8 __attribute__((ext_vector_type(8)));
typedef __fp16 p2 __attribute__((ext_vector_type(2)));
typedef float f32x4 __attribute__((ext_vector_type(4)));

union PK { p2 p; unsigned u; };
union FragA { f16x8 v; p2 p[4]; };

static __device__ __forceinline__ unsigned pku(float a, float b) {
  PK z; z.p = __builtin_amdgcn_cvt_pkrtz(a, b); return z.u;
}

__global__ __launch_bounds__(NT, 5)
void corr_kernel(const float* __restrict__ x1g, const float* __restrict__ x2g,
                 float* __restrict__ outg) {
  constexpr int Cc = 128, Hh = 192, Ww = 192;
  constexpr int HW = Hh * Ww;
  constexpr int ROWU = 384;   // uints per rho row: 24 j * 16 cpair
  constexpr int BUFU = 2560;  // uints per buffer (6*384=2304 + jt1 overread pad)

  __shared__ __align__(16) unsigned sm[2 * BUFU];  // 20.5 KB

  // XCD-chunked: 13824 = 8 XCDs x 1728; XCD k == batch k (1728 = 12xt*48yt*3g).
  const int bid = blockIdx.x;
  const int wid = (bid & 7) * 1728 + (bid >> 3);
  const int g2 = wid % 3;          // dy-triple index
  const int r1 = wid / 3;
  const int yt = r1 % 48;
  const int r2 = r1 / 48;
  const int xt = r2 % 12;
  const int b  = r2 / 12;
  const int y0 = yt * 4, x0 = xt * 16, dyB = g2 * 3;

  const int tid = (int)threadIdx.x;
  const int wy = tid >> 6;     // wave = y row (0..3)
  const int lane = tid & 63;
  const int lr = lane & 15;    // A row p / B col n
  const int lq = lane >> 4;    // k-block

  // ---- A fragments: x1[c][y0+wy][x0+lr], c = kc*32 + lq*8 + e ----
  FragA af[4];
  {
    const float* pA = x1g + (((size_t)b * Cc) * Hh + (y0 + wy)) * Ww + x0 + lr;
#pragma unroll
    for (int kc = 0; kc < 4; ++kc)
#pragma unroll
      for (int r = 0; r < 4; ++r) {
        const int c0 = kc * 32 + lq * 8 + 2 * r;
        af[kc].p[r] = __builtin_amdgcn_cvt_pkrtz(pA[(size_t)c0 * HW],
                                                 pA[(size_t)(c0 + 1) * HW]);
      }
  }

  // ---- staging: 576 slots = 6 i x 16 cpair x 6 jf; 3 slots/thread ----
  const float* bsrc[3];
  int loff[3];
  bool ok[3], has[3];
#pragma unroll
  for (int k = 0; k < 3; ++k) {
    const int s = tid + k * NT;
    has[k] = (s < 576);
    const int jf = s % 6;
    const int t = s / 6;
    const int cp = t & 15;
    const int i = (t >> 4) & 7;  // 0..5 for valid slots
    const int grow = y0 + dyB - 4 + i;
    const int gcol = x0 - 4 + 4 * jf;
    ok[k] = has[k] && grow >= 0 && grow < Hh && gcol >= 0 && gcol <= Ww - 4;
    const int rc = min(max(grow, 0), Hh - 1);
    const int cc = min(max(gcol, 0), Ww - 4);
    bsrc[k] = x2g + ((size_t)(b * Cc + 2 * cp) * Hh + rc) * Ww + cc;
    // [i][j=4jf+jj][cpair] with cq XOR-swizzled by jf&3 (stores at +16*jj)
    loff[k] = i * ROWU + (4 * jf) * 16 + (((cp >> 2) ^ (jf & 3)) << 2) + (cp & 3);
  }

  unsigned pk[3][4];
  auto bload = [&](int kc) {
#pragma unroll
    for (int k = 0; k < 3; ++k) {
      float4 v0 = make_float4(0.f, 0.f, 0.f, 0.f), v1 = v0;
      if (ok[k]) {
        const float* p = bsrc[k] + (size_t)(kc * 32) * HW;
        v0 = *(const float4*)p;         // channel 2cp, cols j..j+3
        v1 = *(const float4*)(p + HW);  // channel 2cp+1
      }
      pk[k][0] = pku(v0.x, v1.x);
      pk[k][1] = pku(v0.y, v1.y);
      pk[k][2] = pku(v0.z, v1.z);
      pk[k][3] = pku(v0.w, v1.w);
    }
  };
  auto bwrite = [&](int buf) {
    unsigned* d = sm + buf * BUFU;
#pragma unroll
    for (int k = 0; k < 3; ++k)
      if (has[k]) {
#pragma unroll
        for (int jj = 0; jj < 4; ++jj) d[loff[k] + jj * 16] = pk[k][jj];
      }
  };

  f32x4 acc[3][2];
#pragma unroll
  for (int d = 0; d < 3; ++d)
#pragma unroll
    for (int jt = 0; jt < 2; ++jt)
      acc[d][jt] = (f32x4){0.f, 0.f, 0.f, 0.f};

  bload(0);
  bwrite(0);
  bload(1);

  // B-frag read offsets (uints): j*16 + swizzled cq*4; key (j>>2)&3 == (lr>>2)&3
  const int swz = (lq ^ ((lr >> 2) & 3)) << 2;
  const int rb0 = lr * 16 + swz;         // jt0: j = lr
  const int rb1 = (16 + lr) * 16 + swz;  // jt1: j = 16+lr

#pragma unroll
  for (int kc = 0; kc < 4; ++kc) {
    __syncthreads();                        // buf[kc&1] (chunk kc) ready
    if (kc < 3) bwrite((kc + 1) & 1);       // publish chunk kc+1
    if (kc < 2) bload(kc + 2);              // issue chunk kc+2 loads
    const unsigned* base = sm + (kc & 1) * BUFU;
#pragma unroll
    for (int d = 0; d < 3; ++d) {
      const unsigned* rp = base + (wy + d) * ROWU;
      const f16x8 b0 = *(const f16x8*)(rp + rb0);
      const f16x8 b1 = *(const f16x8*)(rp + rb1);
      acc[d][0] =
          __builtin_amdgcn_mfma_f32_16x16x32_f16(af[kc].v, b0, acc[d][0], 0, 0, 0);
      acc[d][1] =
          __builtin_amdgcn_mfma_f32_16x16x32_f16(af[kc].v, b1, acc[d][1], 0, 0, 0);
    }
  }

  // ---- epilogue: band extract -> LDS out-tile [27][4][16] -> coalesced ----
  __syncthreads();
  float* ot = (float*)sm;  // 1728 floats = 6.9 KB
  const float invc = 1.0f / 128.0f;
#pragma unroll
  for (int d = 0; d < 3; ++d)
#pragma unroll
    for (int jt = 0; jt < 2; ++jt)
#pragma unroll
      for (int r = 0; r < 4; ++r) {
        const int p = 4 * lq + r;         // x pixel (C row)
        const int dx = jt * 16 + lr - p;  // C col - row
        if (dx >= 0 && dx <= 8)
          ot[((d * 9 + dx) * 4 + wy) * 16 + p] = acc[d][jt][r] * invc;
      }
  __syncthreads();

  for (int s = tid; s < 432; s += NT) {  // 27 planes x 4 y x 4 float4
    const int p27 = s >> 4;
    const int yy = (s >> 2) & 3;
    const int xf = s & 3;
    const float4 v = *(const float4*)&ot[p27 * 64 + yy * 16 + xf * 4];
    *(float4*)&outg[(((size_t)b * 81 + dyB * 9 + p27) * Hh + (y0 + yy)) * Ww +
                    x0 + 4 * xf] = v;
  }
}

extern "C" void kernel_launch(void* const* d_in, const int* in_sizes, int n_in,
                              void* d_out, int out_size, void* d_ws, size_t ws_size,
                              hipStream_t stream) {
  const float* x1 = (const float*)d_in[0];
  const float* x2 = (const float*)d_in[1];
  float* out = (float*)d_out;
  // grid: 8b x 12xt x 48yt x 3 dy-triples = 13824 blocks (divisible by 8 XCDs)
  corr_kernel<<<dim3(13824), dim3(NT), 0, stream>>>(x1, x2, out);
}

// Round 14
// 186.651 us; speedup vs baseline: 1.4650x; 1.0870x over previous
//
#include <hip/hip_runtime.h>

// Correlation (FlowNet-style), kernel=1, stride=1, md=pad=4.
// B=8, C=128, H=W=192 -> out [8, 81, 192, 192] fp32.
//
// Round-14: R11 band-GEMM with conflict-free-write staging + smaller LDS.
//  - block (b, 8y, 16x), 512 thr = 8 waves (wave = y row); 2304 blocks,
//    XCD-chunked swizzle (XCD k == batch k).
//  - x2 LDS rows [rho 16][j 24][cpair 16] uints; uint(j*16+cp) = f16 pair
//    (ch 2cp, 2cp+1) of column j. Row stride 384 uints.
//    READ:  lane (lr,lq) reads uints row + lr*16 + lq*4 (+256 for jt1):
//           64 lanes = contiguous 1024 B -> conflict-free (R11-validated).
//    WRITE: slot s -> cpair = s&15 (bank = lane&15 +16*(kk&1)): 4-way
//           residual (was 6-way via jf-fastest mapping in R11).
//  - j 24..31 unstaged: jt1 lanes lr>=8 read pad garbage; their dx > 8 ->
//    never stored. Buffer padded to 6400 uints so overreads stay in LDS.
//  - 2 x 25.6 KB buffers = 51.2 KB -> 3 blocks/CU (was 2 at 64 KB).
//  - A-frags: x1 scalar f32 + cvt_pkrtz, 4 K-chunks in 16 VGPR (validated).
//  - acc[9 dy][2 jt] f32x4; K-loop kc=0..3 fully unrolled, dbuf, loads
//    issued 2 chunks ahead.
//  - epilogue: band scatter -> LDS out-tile [81][8][16] -> coalesced f4.

#define NT 512

typedef __fp16 f16x8 __attribute__((ext_vector_type(8)));
typedef __fp16 p2 __attribute__((ext_vector_type(2)));
typedef float f32x4 __attribute__((ext_vector_type(4)));

union PK { p2 p; unsigned u; };
union FragA { f16x8 v; p2 p[4]; };

static __device__ __forceinline__ unsigned pku(float a, float b) {
  PK z; z.p = __builtin_amdgcn_cvt_pkrtz(a, b); return z.u;
}

__global__ __launch_bounds__(NT, 4)
void corr_kernel(const float* __restrict__ x1g, const float* __restrict__ x2g,
                 float* __restrict__ outg) {
  constexpr int Cc = 128, Hh = 192, Ww = 192;
  constexpr int HW = Hh * Ww;
  constexpr int ROWU = 384;   // uints per rho row (24 j * 16 cpair)
  constexpr int BUFU = 6400;  // 16*384 = 6144 + 256 pad for jt1 overread

  __shared__ __align__(16) unsigned sm[2 * BUFU];  // 51.2 KB

  // XCD-chunked swizzle: 2304 = 8 XCDs x 288; yt fastest.
  const int bid = blockIdx.x;
  const int wid = (bid & 7) * 288 + (bid >> 3);
  const int yt = wid % 24;
  const int t2 = wid / 24;
  const int xbk = t2 % 12;
  const int b = t2 / 12;
  const int y0 = yt * 8, x0 = xbk * 16;

  const int tid = (int)threadIdx.x;
  const int wy = tid >> 6;      // wave = y row
  const int lane = tid & 63;
  const int lr = lane & 15;     // A row p / B col n
  const int lq = lane >> 4;     // k-block

  // ---- A fragments: x1[c][y0+wy][x0+lr], c = kc*32 + lq*8 + e ----
  FragA af[4];
  {
    const float* pA = x1g + (((size_t)b * Cc) * Hh + (y0 + wy)) * Ww + x0 + lr;
#pragma unroll
    for (int kc = 0; kc < 4; ++kc)
#pragma unroll
      for (int r = 0; r < 4; ++r) {
        const int c0 = kc * 32 + lq * 8 + 2 * r;
        af[kc].p[r] = __builtin_amdgcn_cvt_pkrtz(pA[(size_t)c0 * HW],
                                                 pA[(size_t)(c0 + 1) * HW]);
      }
  }

  // ---- staging: 1536 slots; s -> cpair = s&15 (bank-spread), jf, rho ----
  const float* bsrc[3];
  int loff[3];
  bool ok[3];
#pragma unroll
  for (int k = 0; k < 3; ++k) {
    const int s = tid + k * NT;
    const int cp = s & 15;
    const int t = s >> 4;            // 0..95
    const int jf = t % 6;            // float4 col group (j = 4jf+kk)
    const int rho = t / 6;           // 0..15
    const int grow = y0 - 4 + rho;
    const int gcol = x0 - 4 + 4 * jf;
    ok[k] = (grow >= 0) && (grow < Hh) && (gcol >= 0) && (gcol <= Ww - 4);
    const int rc = min(max(grow, 0), Hh - 1);
    const int cc = min(max(gcol, 0), Ww - 4);
    bsrc[k] = x2g + ((size_t)(b * Cc + 2 * cp) * Hh + rc) * Ww + cc;
    loff[k] = rho * ROWU + (4 * jf) * 16 + cp;  // +16*kk per column
  }

  unsigned pk[3][4];
  auto bload = [&](int kc) {
#pragma unroll
    for (int k = 0; k < 3; ++k) {
      float4 v0 = make_float4(0.f, 0.f, 0.f, 0.f), v1 = v0;
      if (ok[k]) {
        const float* p = bsrc[k] + (size_t)(kc * 32) * HW;
        v0 = *(const float4*)p;         // channel 2cp, cols j..j+3
        v1 = *(const float4*)(p + HW);  // channel 2cp+1
      }
      pk[k][0] = pku(v0.x, v1.x);
      pk[k][1] = pku(v0.y, v1.y);
      pk[k][2] = pku(v0.z, v1.z);
      pk[k][3] = pku(v0.w, v1.w);
    }
  };
  auto bwrite = [&](int buf) {
    unsigned* d = sm + buf * BUFU;
#pragma unroll
    for (int k = 0; k < 3; ++k)
#pragma unroll
      for (int kk = 0; kk < 4; ++kk)
        d[loff[k] + kk * 16] = pk[k][kk];
  };

  f32x4 acc[9][2];
#pragma unroll
  for (int dy = 0; dy < 9; ++dy)
#pragma unroll
    for (int jt = 0; jt < 2; ++jt)
      acc[dy][jt] = (f32x4){0.f, 0.f, 0.f, 0.f};

  bload(0);
  bwrite(0);
  bload(1);

  const int rb = lr * 16 + lq * 4;  // uints; wave covers contiguous 1 KB

#pragma unroll
  for (int kc = 0; kc < 4; ++kc) {
    __syncthreads();                       // buf[kc&1] (chunk kc) ready
    if (kc + 1 < 4) bwrite((kc + 1) & 1);  // publish chunk kc+1
    if (kc + 2 < 4) bload(kc + 2);         // issue chunk kc+2 loads
    const unsigned* base = sm + (kc & 1) * BUFU;
#pragma unroll
    for (int dy = 0; dy < 9; ++dy) {
      const unsigned* rp = base + (wy + dy) * ROWU + rb;
      const f16x8 b0 = *(const f16x8*)(rp);        // j = lr
      const f16x8 b1 = *(const f16x8*)(rp + 256);  // j = 16+lr (lr>=8: pad)
      acc[dy][0] = __builtin_amdgcn_mfma_f32_16x16x32_f16(af[kc].v, b0,
                                                          acc[dy][0], 0, 0, 0);
      acc[dy][1] = __builtin_amdgcn_mfma_f32_16x16x32_f16(af[kc].v, b1,
                                                          acc[dy][1], 0, 0, 0);
    }
  }

  // ---- epilogue: band extract -> LDS out-tile [81][8][16] -> coalesced ----
  __syncthreads();
  float* ot = (float*)sm;  // 41472 B <= 51.2 KB
  const float invc = 1.0f / 128.0f;
#pragma unroll
  for (int dy = 0; dy < 9; ++dy)
#pragma unroll
    for (int jt = 0; jt < 2; ++jt)
#pragma unroll
      for (int r = 0; r < 4; ++r) {
        const int p = 4 * lq + r;         // x pixel (C row)
        const int dx = jt * 16 + lr - p;  // C col - row
        if (dx >= 0 && dx < 9)
          ot[((dy * 9 + dx) * 8 + wy) * 16 + p] = acc[dy][jt][r] * invc;
      }
  __syncthreads();

  for (int s = tid; s < 2592; s += NT) {  // 81 d x 8 y x 4 float4
    const int d = s >> 5;
    const int yy = (s >> 2) & 7;
    const int xf = s & 3;
    const float4 v = *(const float4*)&ot[d * 128 + yy * 16 + xf * 4];
    *(float4*)&outg[(((size_t)b * 81 + d) * Hh + (y0 + yy)) * Ww + x0 + 4 * xf] = v;
  }
}

extern "C" void kernel_launch(void* const* d_in, const int* in_sizes, int n_in,
                              void* d_out, int out_size, void* d_ws, size_t ws_size,
                              hipStream_t stream) {
  const float* x1 = (const float*)d_in[0];
  const float* x2 = (const float*)d_in[1];
  float* out = (float*)d_out;
  // grid: 8 b x 24 y-strips x 12 x-tiles = 2304 blocks (divisible by 8 XCDs)
  corr_kernel<<<dim3(2304), dim3(NT), 0, stream>>>(x1, x2, out);
}

// Round 15
// 182.474 us; speedup vs baseline: 1.4985x; 1.0229x over previous
//
#include <hip/hip_runtime.h>

// Correlation (FlowNet-style), kernel=1, stride=1, md=pad=4.
// B=8, C=128, H=W=192 -> out [8, 81, 192, 192] fp32.
//
// Round-15: R11 band-GEMM with a staging transpose that is conflict-free on
// BOTH the global side and the LDS side.
//  - block (b, 8y, 16x), 512 thr = 8 waves (wave = y row); 2304 blocks,
//    XCD-chunked swizzle (XCD k == batch k).
//  - x2 LDS: [rho 16][j 24][cp 16] uints, uint(j*16+cp') = f16 pair; cp-group
//    XOR swizzle cp' = 4*(g^(j&3)) + e.
//    WRITE: slot (rho, g, j): 8 scalar f32 loads (ch 8g..8g+7, col j; lanes
//           sweep j -> 96B runs, coalesced) -> 1 ds_write_b128 at
//           rho*384 + j*16 + ((g^(j&3))<<2); lanes cover all 8 bank-quads
//           evenly -> minimum-phase write (R11: 6-way b32 scatter).
//    READ:  lane (lr,lq) b128 at lr*16 + ((lq^(lr&3))<<2) (+256 jt1):
//           (j&3)==(lr&3) for both j-tiles so the XOR cancels -> channels
//           8lq..8lq+7 in order; bank-quad multiset identical to the
//           contiguous-1KB perfect read.
//  - j 24..31 unstaged (jt1 lanes lr>=8 feed only dx>8, discarded); BUFU
//    padded so overreads stay in LDS.
//  - A-frags: x1 scalar f32 + cvt_pkrtz, 4 K-chunks in 16 VGPR (validated).
//  - acc[9 dy][2 jt] f32x4; kc fully unrolled, dbuf, loads 2 chunks ahead.
//  - epilogue: band scatter -> LDS out-tile [81][8][16] -> coalesced f4.

#define NT 512

typedef __fp16 f16x8 __attribute__((ext_vector_type(8)));
typedef __fp16 p2 __attribute__((ext_vector_type(2)));
typedef float f32x4 __attribute__((ext_vector_type(4)));

union PK { p2 p; unsigned u; };
union FragA { f16x8 v; p2 p[4]; };

static __device__ __forceinline__ unsigned pku(float a, float b) {
  PK z; z.p = __builtin_amdgcn_cvt_pkrtz(a, b); return z.u;
}

__global__ __launch_bounds__(NT, 4)
void corr_kernel(const float* __restrict__ x1g, const float* __restrict__ x2g,
                 float* __restrict__ outg) {
  constexpr int Cc = 128, Hh = 192, Ww = 192;
  constexpr int HW = Hh * Ww;
  constexpr int ROWU = 384;   // uints per rho row (24 j * 16 cp)
  constexpr int BUFU = 6400;  // 16*384 = 6144 + 256 pad for jt1 overread

  __shared__ __align__(16) unsigned sm[2 * BUFU];  // 51.2 KB

  // XCD-chunked swizzle: 2304 = 8 XCDs x 288; yt fastest.
  const int bid = blockIdx.x;
  const int wid = (bid & 7) * 288 + (bid >> 3);
  const int yt = wid % 24;
  const int t2 = wid / 24;
  const int xbk = t2 % 12;
  const int b = t2 / 12;
  const int y0 = yt * 8, x0 = xbk * 16;

  const int tid = (int)threadIdx.x;
  const int wy = tid >> 6;      // wave = y row
  const int lane = tid & 63;
  const int lr = lane & 15;     // A row p / B col n
  const int lq = lane >> 4;     // k-block

  // ---- A fragments: x1[c][y0+wy][x0+lr], c = kc*32 + lq*8 + e ----
  FragA af[4];
  {
    const float* pA = x1g + (((size_t)b * Cc) * Hh + (y0 + wy)) * Ww + x0 + lr;
#pragma unroll
    for (int kc = 0; kc < 4; ++kc)
#pragma unroll
      for (int r = 0; r < 4; ++r) {
        const int c0 = kc * 32 + lq * 8 + 2 * r;
        af[kc].p[r] = __builtin_amdgcn_cvt_pkrtz(pA[(size_t)c0 * HW],
                                                 pA[(size_t)(c0 + 1) * HW]);
      }
  }

  // ---- staging: 1536 slots = 16 rho x 4 g x 24 j; j fastest ----
  const float* bsrc[3];
  int loff[3];
  bool ok[3];
#pragma unroll
  for (int k = 0; k < 3; ++k) {
    const int s = tid + k * NT;
    const int j = s % 24;
    const int t = s / 24;
    const int g = t & 3;          // cp-group (channels 8g..8g+7)
    const int rho = t >> 2;       // 0..15
    const int grow = y0 - 4 + rho;
    const int gcol = x0 - 4 + j;
    ok[k] = (grow >= 0) && (grow < Hh) && (gcol >= 0) && (gcol < Ww);
    const int rc = min(max(grow, 0), Hh - 1);
    const int cl = min(max(gcol, 0), Ww - 1);
    bsrc[k] = x2g + ((size_t)(b * Cc + 8 * g) * Hh + rc) * Ww + cl;
    loff[k] = rho * ROWU + j * 16 + ((g ^ (j & 3)) << 2);
  }

  unsigned pk[3][4];
  auto bload = [&](int kc) {
#pragma unroll
    for (int k = 0; k < 3; ++k) {
      float f[8];
      if (ok[k]) {
        const float* p = bsrc[k] + (size_t)(kc * 32) * HW;
#pragma unroll
        for (int e = 0; e < 8; ++e) f[e] = p[(size_t)e * HW];
      } else {
#pragma unroll
        for (int e = 0; e < 8; ++e) f[e] = 0.f;
      }
      pk[k][0] = pku(f[0], f[1]);
      pk[k][1] = pku(f[2], f[3]);
      pk[k][2] = pku(f[4], f[5]);
      pk[k][3] = pku(f[6], f[7]);
    }
  };
  auto bwrite = [&](int buf) {
    unsigned* d = sm + buf * BUFU;
#pragma unroll
    for (int k = 0; k < 3; ++k) {
      uint4 v;
      v.x = pk[k][0]; v.y = pk[k][1]; v.z = pk[k][2]; v.w = pk[k][3];
      *(uint4*)&d[loff[k]] = v;  // single b128, even 8-quad spread
    }
  };

  f32x4 acc[9][2];
#pragma unroll
  for (int dy = 0; dy < 9; ++dy)
#pragma unroll
    for (int jt = 0; jt < 2; ++jt)
      acc[dy][jt] = (f32x4){0.f, 0.f, 0.f, 0.f};

  bload(0);
  bwrite(0);
  bload(1);

  // read: XOR cancels ((j&3)==(lr&3)) -> channels 8lq..8lq+7 in order
  const int rb = lr * 16 + ((lq ^ (lr & 3)) << 2);

#pragma unroll
  for (int kc = 0; kc < 4; ++kc) {
    __syncthreads();                       // buf[kc&1] (chunk kc) ready
    if (kc + 1 < 4) bwrite((kc + 1) & 1);  // publish chunk kc+1
    if (kc + 2 < 4) bload(kc + 2);         // issue chunk kc+2 loads
    const unsigned* base = sm + (kc & 1) * BUFU;
#pragma unroll
    for (int dy = 0; dy < 9; ++dy) {
      const unsigned* rp = base + (wy + dy) * ROWU + rb;
      const f16x8 b0 = *(const f16x8*)(rp);        // j = lr
      const f16x8 b1 = *(const f16x8*)(rp + 256);  // j = 16+lr (lr>=8: pad)
      acc[dy][0] = __builtin_amdgcn_mfma_f32_16x16x32_f16(af[kc].v, b0,
                                                          acc[dy][0], 0, 0, 0);
      acc[dy][1] = __builtin_amdgcn_mfma_f32_16x16x32_f16(af[kc].v, b1,
                                                          acc[dy][1], 0, 0, 0);
    }
  }

  // ---- epilogue: band extract -> LDS out-tile [81][8][16] -> coalesced ----
  __syncthreads();
  float* ot = (float*)sm;  // 41472 B <= 51.2 KB
  const float invc = 1.0f / 128.0f;
#pragma unroll
  for (int dy = 0; dy < 9; ++dy)
#pragma unroll
    for (int jt = 0; jt < 2; ++jt)
#pragma unroll
      for (int r = 0; r < 4; ++r) {
        const int p = 4 * lq + r;         // x pixel (C row)
        const int dx = jt * 16 + lr - p;  // C col - row
        if (dx >= 0 && dx < 9)
          ot[((dy * 9 + dx) * 8 + wy) * 16 + p] = acc[dy][jt][r] * invc;
      }
  __syncthreads();

  for (int s = tid; s < 2592; s += NT) {  // 81 d x 8 y x 4 float4
    const int d = s >> 5;
    const int yy = (s >> 2) & 7;
    const int xf = s & 3;
    const float4 v = *(const float4*)&ot[d * 128 + yy * 16 + xf * 4];
    *(float4*)&outg[(((size_t)b * 81 + d) * Hh + (y0 + yy)) * Ww + x0 + 4 * xf] = v;
  }
}

extern "C" void kernel_launch(void* const* d_in, const int* in_sizes, int n_in,
                              void* d_out, int out_size, void* d_ws, size_t ws_size,
                              hipStream_t stream) {
  const float* x1 = (const float*)d_in[0];
  const float* x2 = (const float*)d_in[1];
  float* out = (float*)d_out;
  // grid: 8 b x 24 y-strips x 12 x-tiles = 2304 blocks (divisible by 8 XCDs)
  corr_kernel<<<dim3(2304), dim3(NT), 0, stream>>>(x1, x2, out);
}

// Round 17
// 172.083 us; speedup vs baseline: 1.5890x; 1.0604x over previous
//
#include <hip/hip_runtime.h>

// Correlation (FlowNet-style), kernel=1, stride=1, md=pad=4.
// B=8, C=128, H=W=192 -> out [8, 81, 192, 192] fp32.
//
// Round-17: R16 with the double-buffer indexing bug fixed (bwrite takes a
// BUFFER index; R16 passed chunk numbers 2/3 -> wrote past the LDS array,
// chunks 2,3 never published -> absmax 0.54).
//  Deltas vs R11 (187 us/dispatch baseline):
//  (a) epilogue out-tile plane stride 132 (was 128): band-scatter banks get
//      +4*dx per-lane spread -> targets the ~2e7 epilogue conflict cycles
//      (R14/R15: identical 1.969e7 across different staging layouts).
//  (b) two pk register sets + prologue loads for chunks 0,1,2: every LDS
//      publish consumes global loads issued >=1.5 chunks earlier.
//  (c) LDS row compaction 512 -> 384 uints -> 51.2 KB total.

#define NT 512

typedef __fp16 f16x8 __attribute__((ext_vector_type(8)));
typedef __fp16 p2 __attribute__((ext_vector_type(2)));
typedef float f32x4 __attribute__((ext_vector_type(4)));

union PK { p2 p; unsigned u; };
union FragA { f16x8 v; p2 p[4]; };

static __device__ __forceinline__ unsigned pku(float a, float b) {
  PK z; z.p = __builtin_amdgcn_cvt_pkrtz(a, b); return z.u;
}

__global__ __launch_bounds__(NT, 4)
void corr_kernel(const float* __restrict__ x1g, const float* __restrict__ x2g,
                 float* __restrict__ outg) {
  constexpr int Cc = 128, Hh = 192, Ww = 192;
  constexpr int HW = Hh * Ww;
  constexpr int ROWU = 384;   // uints per rho row (j 0..23 x 16 cp)
  constexpr int BUFU = 6400;  // 16*384 + 256 pad for jt1 overread
  constexpr int PS = 132;     // epilogue plane stride (floats)

  __shared__ __align__(16) unsigned sm[2 * BUFU];  // 51.2 KB

  // XCD-chunked swizzle: 2304 = 8 XCDs x 288; yt fastest.
  const int bid = blockIdx.x;
  const int wid = (bid & 7) * 288 + (bid >> 3);
  const int yt = wid % 24;
  const int t2 = wid / 24;
  const int xbk = t2 % 12;
  const int b = t2 / 12;
  const int y0 = yt * 8, x0 = xbk * 16;

  const int tid = (int)threadIdx.x;
  const int wy = tid >> 6;      // wave = y row
  const int lane = tid & 63;
  const int lr = lane & 15;     // A row p / B col n
  const int lq = lane >> 4;     // k-block

  // ---- A fragments: x1[c][y0+wy][x0+lr], c = kc*32 + lq*8 + e ----
  FragA af[4];
  {
    const float* pA = x1g + (((size_t)b * Cc) * Hh + (y0 + wy)) * Ww + x0 + lr;
#pragma unroll
    for (int kc = 0; kc < 4; ++kc)
#pragma unroll
      for (int r = 0; r < 4; ++r) {
        const int c0 = kc * 32 + lq * 8 + 2 * r;
        af[kc].p[r] = __builtin_amdgcn_cvt_pkrtz(pA[(size_t)c0 * HW],
                                                 pA[(size_t)(c0 + 1) * HW]);
      }
  }

  // ---- staging slots (R11 mapping): s -> jf = s%6, cp = (s/6)&15, rho ----
  const float* bsrc[3];
  int loff[3];
  bool ok[3];
#pragma unroll
  for (int k = 0; k < 3; ++k) {
    const int s = tid + k * NT;
    const int jf = s % 6;
    const int t = s / 6;
    const int cp = t & 15;
    const int rho = t >> 4;          // 0..15
    const int grow = y0 - 4 + rho;
    const int gcol = x0 - 4 + 4 * jf;
    ok[k] = (grow >= 0) && (grow < Hh) && (gcol >= 0) && (gcol <= Ww - 4);
    bsrc[k] = x2g + ((size_t)(b * Cc + 2 * cp) * Hh + (ok[k] ? grow : 0)) * Ww +
              (ok[k] ? gcol : 0);
    loff[k] = rho * ROWU + jf * 64 + cp;  // +16*kk per column j = 4jf+kk
  }

  unsigned pkA[3][4], pkB[3][4];

  auto bload = [&](int kc, unsigned (&pk)[3][4]) {
#pragma unroll
    for (int k = 0; k < 3; ++k) {
      float4 v0 = make_float4(0.f, 0.f, 0.f, 0.f), v1 = v0;
      if (ok[k]) {
        const float* p = bsrc[k] + (size_t)(kc * 32) * HW;
        v0 = *(const float4*)p;         // channel 2cp, cols j..j+3
        v1 = *(const float4*)(p + HW);  // channel 2cp+1
      }
      pk[k][0] = pku(v0.x, v1.x);
      pk[k][1] = pku(v0.y, v1.y);
      pk[k][2] = pku(v0.z, v1.z);
      pk[k][3] = pku(v0.w, v1.w);
    }
  };
  auto bwrite = [&](int buf, unsigned (&pk)[3][4]) {
    unsigned* d = sm + buf * BUFU;   // buf MUST be 0 or 1
#pragma unroll
    for (int k = 0; k < 3; ++k)
#pragma unroll
      for (int kk = 0; kk < 4; ++kk)
        d[loff[k] + kk * 16] = pk[k][kk];
  };

  f32x4 acc[9][2];
#pragma unroll
  for (int dy = 0; dy < 9; ++dy)
#pragma unroll
    for (int jt = 0; jt < 2; ++jt)
      acc[dy][jt] = (f32x4){0.f, 0.f, 0.f, 0.f};

  // deep prologue: chunk0 published; chunk1 in pkA, chunk2 in pkB (in flight)
  bload(0, pkA);
  bwrite(0, pkA);
  bload(1, pkA);
  bload(2, pkB);

  const int rb = lr * 16 + lq * 4;  // uints; wave covers contiguous 1 KB

#pragma unroll
  for (int kc = 0; kc < 4; ++kc) {
    __syncthreads();  // buf[kc&1] (chunk kc) ready; prior readers done
    if (kc == 0) {
      bwrite(1, pkA);   // chunk1 -> buf1
      bload(3, pkA);    // chunk3 into pkA
    } else if (kc == 1) {
      bwrite(0, pkB);   // chunk2 -> buf0 (issued 2 phases ago)
    } else if (kc == 2) {
      bwrite(1, pkA);   // chunk3 -> buf1 (issued 2 phases ago)
    }
    const unsigned* base = sm + (kc & 1) * BUFU;
#pragma unroll
    for (int dy = 0; dy < 9; ++dy) {
      const unsigned* rp = base + (wy + dy) * ROWU + rb;
      const f16x8 b0 = *(const f16x8*)(rp);        // j = lr
      const f16x8 b1 = *(const f16x8*)(rp + 256);  // j = 16+lr (lr>=8: pad)
      acc[dy][0] = __builtin_amdgcn_mfma_f32_16x16x32_f16(af[kc].v, b0,
                                                          acc[dy][0], 0, 0, 0);
      acc[dy][1] = __builtin_amdgcn_mfma_f32_16x16x32_f16(af[kc].v, b1,
                                                          acc[dy][1], 0, 0, 0);
    }
  }

  // ---- epilogue: band extract -> LDS out-tile [81][PS] -> coalesced f4 ----
  __syncthreads();
  float* ot = (float*)sm;  // 81*132*4 = 42768 B <= 51.2 KB
  const float invc = 1.0f / 128.0f;
#pragma unroll
  for (int dy = 0; dy < 9; ++dy)
#pragma unroll
    for (int jt = 0; jt < 2; ++jt)
#pragma unroll
      for (int r = 0; r < 4; ++r) {
        const int p = 4 * lq + r;         // x pixel (C row)
        const int dx = jt * 16 + lr - p;  // C col - row
        if (dx >= 0 && dx < 9)
          ot[(dy * 9 + dx) * PS + wy * 16 + p] = acc[dy][jt][r] * invc;
      }
  __syncthreads();

  for (int s = tid; s < 2592; s += NT) {  // 81 d x 8 y x 4 float4
    const int d = s >> 5;
    const int yy = (s >> 2) & 7;
    const int xf = s & 3;
    const float4 v = *(const float4*)&ot[d * PS + yy * 16 + xf * 4];
    *(float4*)&outg[(((size_t)b * 81 + d) * Hh + (y0 + yy)) * Ww + x0 + 4 * xf] = v;
  }
}

extern "C" void kernel_launch(void* const* d_in, const int* in_sizes, int n_in,
                              void* d_out, int out_size, void* d_ws, size_t ws_size,
                              hipStream_t stream) {
  const float* x1 = (const float*)d_in[0];
  const float* x2 = (const float*)d_in[1];
  float* out = (float*)d_out;
  // grid: 8 b x 24 y-strips x 12 x-tiles = 2304 blocks (divisible by 8 XCDs)
  corr_kernel<<<dim3(2304), dim3(NT), 0, stream>>>(x1, x2, out);
}

// Round 18
// 125.601 us; speedup vs baseline: 2.1770x; 1.3701x over previous
//
#include <hip/hip_runtime.h>

// Correlation (FlowNet-style), kernel=1, stride=1, md=pad=4.
// B=8, C=128, H=W=192 -> out [8, 81, 192, 192] fp32.
//
// Round-18: R17 with ONE change — block-order swizzle puts xbk (x-tile)
// fastest instead of yt. Rationale (counter-driven): FETCH=505 MB vs 302
// compulsory. With yt-fastest, the ~54 concurrent blocks per XCD span ~2.5
// full yt-columns -> per-K-chunk L2 footprint ~6.75 MB > 4 MB -> x2 y-halos
// (2x amplification) and x1 64-B half-lines never get shared. With
// xbk-fastest, concurrent blocks = ~4.5 yt rows x 12 xbk -> footprint
// ~2.2 MB < 4 MB L2 -> x1 128-B line pairing + x2 halo reuse become hits.
// XCD k still == batch k (288 = 12*24 per batch).
//
// Everything else is R17-verbatim (187-190 us/dispatch baseline): f16 MFMA
// band-GEMM, [rho16][j24][cp16] staging (float4 loads, jf=s%6 map),
// contiguous-1KB frag reads, acc[9][2], 4-chunk dbuf with deep prologue,
// stride-132 epilogue out-tile.

#define NT 512

typedef __fp16 f16x8 __attribute__((ext_vector_type(8)));
typedef __fp16 p2 __attribute__((ext_vector_type(2)));
typedef float f32x4 __attribute__((ext_vector_type(4)));

union PK { p2 p; unsigned u; };
union FragA { f16x8 v; p2 p[4]; };

static __device__ __forceinline__ unsigned pku(float a, float b) {
  PK z; z.p = __builtin_amdgcn_cvt_pkrtz(a, b); return z.u;
}

__global__ __launch_bounds__(NT, 4)
void corr_kernel(const float* __restrict__ x1g, const float* __restrict__ x2g,
                 float* __restrict__ outg) {
  constexpr int Cc = 128, Hh = 192, Ww = 192;
  constexpr int HW = Hh * Ww;
  constexpr int ROWU = 384;   // uints per rho row (j 0..23 x 16 cp)
  constexpr int BUFU = 6400;  // 16*384 + 256 pad for jt1 overread
  constexpr int PS = 132;     // epilogue plane stride (floats)

  __shared__ __align__(16) unsigned sm[2 * BUFU];  // 51.2 KB

  // XCD-chunked swizzle: 2304 = 8 XCDs x 288; *** xbk fastest *** so the
  // concurrently-resident blocks of an XCD tile a horizontal band ->
  // per-chunk working set fits the 4 MB XCD L2 (x1 lines + x2 halos shared).
  const int bid = blockIdx.x;
  const int wid = (bid & 7) * 288 + (bid >> 3);
  const int xbk = wid % 12;
  const int t2 = wid / 12;
  const int yt = t2 % 24;
  const int b = t2 / 24;
  const int y0 = yt * 8, x0 = xbk * 16;

  const int tid = (int)threadIdx.x;
  const int wy = tid >> 6;      // wave = y row
  const int lane = tid & 63;
  const int lr = lane & 15;     // A row p / B col n
  const int lq = lane >> 4;     // k-block

  // ---- A fragments: x1[c][y0+wy][x0+lr], c = kc*32 + lq*8 + e ----
  FragA af[4];
  {
    const float* pA = x1g + (((size_t)b * Cc) * Hh + (y0 + wy)) * Ww + x0 + lr;
#pragma unroll
    for (int kc = 0; kc < 4; ++kc)
#pragma unroll
      for (int r = 0; r < 4; ++r) {
        const int c0 = kc * 32 + lq * 8 + 2 * r;
        af[kc].p[r] = __builtin_amdgcn_cvt_pkrtz(pA[(size_t)c0 * HW],
                                                 pA[(size_t)(c0 + 1) * HW]);
      }
  }

  // ---- staging slots (R11 mapping): s -> jf = s%6, cp = (s/6)&15, rho ----
  const float* bsrc[3];
  int loff[3];
  bool ok[3];
#pragma unroll
  for (int k = 0; k < 3; ++k) {
    const int s = tid + k * NT;
    const int jf = s % 6;
    const int t = s / 6;
    const int cp = t & 15;
    const int rho = t >> 4;          // 0..15
    const int grow = y0 - 4 + rho;
    const int gcol = x0 - 4 + 4 * jf;
    ok[k] = (grow >= 0) && (grow < Hh) && (gcol >= 0) && (gcol <= Ww - 4);
    bsrc[k] = x2g + ((size_t)(b * Cc + 2 * cp) * Hh + (ok[k] ? grow : 0)) * Ww +
              (ok[k] ? gcol : 0);
    loff[k] = rho * ROWU + jf * 64 + cp;  // +16*kk per column j = 4jf+kk
  }

  unsigned pkA[3][4], pkB[3][4];

  auto bload = [&](int kc, unsigned (&pk)[3][4]) {
#pragma unroll
    for (int k = 0; k < 3; ++k) {
      float4 v0 = make_float4(0.f, 0.f, 0.f, 0.f), v1 = v0;
      if (ok[k]) {
        const float* p = bsrc[k] + (size_t)(kc * 32) * HW;
        v0 = *(const float4*)p;         // channel 2cp, cols j..j+3
        v1 = *(const float4*)(p + HW);  // channel 2cp+1
      }
      pk[k][0] = pku(v0.x, v1.x);
      pk[k][1] = pku(v0.y, v1.y);
      pk[k][2] = pku(v0.z, v1.z);
      pk[k][3] = pku(v0.w, v1.w);
    }
  };
  auto bwrite = [&](int buf, unsigned (&pk)[3][4]) {
    unsigned* d = sm + buf * BUFU;   // buf MUST be 0 or 1
#pragma unroll
    for (int k = 0; k < 3; ++k)
#pragma unroll
      for (int kk = 0; kk < 4; ++kk)
        d[loff[k] + kk * 16] = pk[k][kk];
  };

  f32x4 acc[9][2];
#pragma unroll
  for (int dy = 0; dy < 9; ++dy)
#pragma unroll
    for (int jt = 0; jt < 2; ++jt)
      acc[dy][jt] = (f32x4){0.f, 0.f, 0.f, 0.f};

  // deep prologue: chunk0 published; chunk1 in pkA, chunk2 in pkB (in flight)
  bload(0, pkA);
  bwrite(0, pkA);
  bload(1, pkA);
  bload(2, pkB);

  const int rb = lr * 16 + lq * 4;  // uints; wave covers contiguous 1 KB

#pragma unroll
  for (int kc = 0; kc < 4; ++kc) {
    __syncthreads();  // buf[kc&1] (chunk kc) ready; prior readers done
    if (kc == 0) {
      bwrite(1, pkA);   // chunk1 -> buf1
      bload(3, pkA);    // chunk3 into pkA
    } else if (kc == 1) {
      bwrite(0, pkB);   // chunk2 -> buf0 (issued 2 phases ago)
    } else if (kc == 2) {
      bwrite(1, pkA);   // chunk3 -> buf1 (issued 2 phases ago)
    }
    const unsigned* base = sm + (kc & 1) * BUFU;
#pragma unroll
    for (int dy = 0; dy < 9; ++dy) {
      const unsigned* rp = base + (wy + dy) * ROWU + rb;
      const f16x8 b0 = *(const f16x8*)(rp);        // j = lr
      const f16x8 b1 = *(const f16x8*)(rp + 256);  // j = 16+lr (lr>=8: pad)
      acc[dy][0] = __builtin_amdgcn_mfma_f32_16x16x32_f16(af[kc].v, b0,
                                                          acc[dy][0], 0, 0, 0);
      acc[dy][1] = __builtin_amdgcn_mfma_f32_16x16x32_f16(af[kc].v, b1,
                                                          acc[dy][1], 0, 0, 0);
    }
  }

  // ---- epilogue: band extract -> LDS out-tile [81][PS] -> coalesced f4 ----
  __syncthreads();
  float* ot = (float*)sm;  // 81*132*4 = 42768 B <= 51.2 KB
  const float invc = 1.0f / 128.0f;
#pragma unroll
  for (int dy = 0; dy < 9; ++dy)
#pragma unroll
    for (int jt = 0; jt < 2; ++jt)
#pragma unroll
      for (int r = 0; r < 4; ++r) {
        const int p = 4 * lq + r;         // x pixel (C row)
        const int dx = jt * 16 + lr - p;  // C col - row
        if (dx >= 0 && dx < 9)
          ot[(dy * 9 + dx) * PS + wy * 16 + p] = acc[dy][jt][r] * invc;
      }
  __syncthreads();

  for (int s = tid; s < 2592; s += NT) {  // 81 d x 8 y x 4 float4
    const int d = s >> 5;
    const int yy = (s >> 2) & 7;
    const int xf = s & 3;
    const float4 v = *(const float4*)&ot[d * PS + yy * 16 + xf * 4];
    *(float4*)&outg[(((size_t)b * 81 + d) * Hh + (y0 + yy)) * Ww + x0 + 4 * xf] = v;
  }
}

extern "C" void kernel_launch(void* const* d_in, const int* in_sizes, int n_in,
                              void* d_out, int out_size, void* d_ws, size_t ws_size,
                              hipStream_t stream) {
  const float* x1 = (const float*)d_in[0];
  const float* x2 = (const float*)d_in[1];
  float* out = (float*)d_out;
  // grid: 8 b x 24 y-strips x 12 x-tiles = 2304 blocks (divisible by 8 XCDs)
  corr_kernel<<<dim3(2304), dim3(NT), 0, stream>>>(x1, x2, out);
}